// Round 4
// baseline (717.104 us; speedup 1.0000x reference)
//
#include <hip/hip_runtime.h>

typedef unsigned short u16;
typedef __attribute__((ext_vector_type(8))) short bf16x8;
typedef __attribute__((ext_vector_type(4))) float f32x4;
typedef __attribute__((ext_vector_type(8))) unsigned short u16x8;

#define B_ 2
#define T_ 2048
#define C_ 2048
#define H_ 16
#define D_ 128
#define QKVW 6144  // 3*C

__device__ __forceinline__ u16 f2b(float f) {
  unsigned int x = __builtin_bit_cast(unsigned int, f);
  x += 0x7fffu + ((x >> 16) & 1u);   // round-to-nearest-even
  return (u16)(x >> 16);
}
__device__ __forceinline__ float b2f(u16 u) {
  unsigned int x = ((unsigned int)u) << 16;
  return __builtin_bit_cast(float, x);
}
__device__ __forceinline__ void gl_lds16(const void* g, void* l) {
  __builtin_amdgcn_global_load_lds((const __attribute__((address_space(1))) void*)g,
                                   (__attribute__((address_space(3))) void*)l, 16, 0, 0);
}

// ---------------- cast fp32 -> bf16 (8 elems/thread) ----------------
__global__ void castbf(const float* __restrict__ in, u16* __restrict__ out) {
  int i = blockIdx.x * 256 + threadIdx.x;
  f32x4 a = ((const f32x4*)in)[2 * i];
  f32x4 b = ((const f32x4*)in)[2 * i + 1];
  u16x8 o;
  o[0] = f2b(a[0]); o[1] = f2b(a[1]); o[2] = f2b(a[2]); o[3] = f2b(a[3]);
  o[4] = f2b(b[0]); o[5] = f2b(b[1]); o[6] = f2b(b[2]); o[7] = f2b(b[3]);
  ((u16x8*)out)[i] = o;
}

// ------------- cast + transpose: in [K][N] fp32 -> out [N][K] bf16 -------------
__global__ __launch_bounds__(256) void castT(const float* __restrict__ in,
                                             u16* __restrict__ out, int K, int N) {
  __shared__ __align__(16) u16 ld[64][72];
  const int nt = blockIdx.x * 64, kt = blockIdx.y * 64;
  const int tid = threadIdx.x;
#pragma unroll
  for (int s = 0; s < 4; ++s) {
    int idx = tid + s * 256;        // 0..1023
    int r = idx >> 4;               // k row 0..63
    int c = (idx & 15) * 4;         // n col
    f32x4 v = *(const f32x4*)(in + (size_t)(kt + r) * N + nt + c);
    ld[r][c] = f2b(v[0]); ld[r][c + 1] = f2b(v[1]);
    ld[r][c + 2] = f2b(v[2]); ld[r][c + 3] = f2b(v[3]);
  }
  __syncthreads();
#pragma unroll
  for (int s = 0; s < 2; ++s) {
    int idx = tid + s * 256;        // 0..511
    int n = idx >> 3;               // 0..63
    int c8 = (idx & 7) * 8;         // k offset
    u16x8 o;
#pragma unroll
    for (int j = 0; j < 8; ++j) o[j] = ld[c8 + j][n];
    *(u16x8*)(out + (size_t)(nt + n) * K + kt + c8) = o;
  }
}

// ---------------- GEMM: C[m][n] = sum_k A[m][k] * Bt[n][k], bf16 MFMA ----------------
// 128x128 tile, BK=32, 256 threads = 4 waves (2x2 of 64x64), m97-style staging.
// LDS rows are 4 chunks of 16B; physical chunk = logical ^ (row&3) (bank de-conflict).
template <int OUT_BF16>
__global__ __launch_bounds__(256) void gemm_bt(const u16* __restrict__ A,
                                               const u16* __restrict__ Bt,
                                               void* __restrict__ Cout,
                                               int M, int N, int K) {
  __shared__ __align__(16) u16 lA[128 * 32];
  __shared__ __align__(16) u16 lB[128 * 32];
  const int tid = threadIdx.x;
  const int lane = tid & 63, w = tid >> 6;
  const int quad = lane >> 4, l15 = lane & 15;
  const int tn0 = blockIdx.x * 128, tm0 = blockIdx.y * 128;
  const int wr = (w >> 1) * 64, wc = (w & 1) * 64;
  f32x4 acc[4][4] = {};

  for (int k0 = 0; k0 < K; k0 += 32) {
#pragma unroll
    for (int s = 0; s < 2; ++s) {
      int ch = tid + s * 256;               // 0..511
      int row = ch >> 2, cp = ch & 3;
      int kc = (cp ^ (row & 3)) * 8;        // swizzled global chunk
      gl_lds16(A + (size_t)(tm0 + row) * K + k0 + kc, &lA[ch * 8]);
      gl_lds16(Bt + (size_t)(tn0 + row) * K + k0 + kc, &lB[ch * 8]);
    }
    __syncthreads();
    bf16x8 af[4], bfv[4];
#pragma unroll
    for (int mi = 0; mi < 4; ++mi)
      af[mi] = *(const bf16x8*)&lA[(wr + mi * 16 + l15) * 32 + (quad ^ (l15 & 3)) * 8];
#pragma unroll
    for (int ni = 0; ni < 4; ++ni)
      bfv[ni] = *(const bf16x8*)&lB[(wc + ni * 16 + l15) * 32 + (quad ^ (l15 & 3)) * 8];
#pragma unroll
    for (int mi = 0; mi < 4; ++mi)
#pragma unroll
      for (int ni = 0; ni < 4; ++ni)
        acc[mi][ni] = __builtin_amdgcn_mfma_f32_16x16x32_bf16(af[mi], bfv[ni], acc[mi][ni], 0, 0, 0);
    __syncthreads();
  }
  // epilogue: C/D layout col=lane&15, row=quad*4+reg
#pragma unroll
  for (int mi = 0; mi < 4; ++mi)
#pragma unroll
    for (int ni = 0; ni < 4; ++ni)
#pragma unroll
      for (int r = 0; r < 4; ++r) {
        int row = tm0 + wr + mi * 16 + quad * 4 + r;
        int col = tn0 + wc + ni * 16 + l15;
        float v = acc[mi][ni][r];
        if (OUT_BF16) ((u16*)Cout)[(size_t)row * N + col] = f2b(v);
        else          ((float*)Cout)[(size_t)row * N + col] = v;
      }
}

// ---------------- RoPE in-place on q,k of qkv (bf16) ----------------
__global__ void rope_k(u16* __restrict__ qkv) {
  int idx = blockIdx.x * 256 + threadIdx.x;   // 0 .. 2^23-1
  int i = idx & 63;
  int h = (idx >> 6) & 15;
  int which = (idx >> 10) & 1;
  int t = (idx >> 11) & 2047;
  int b = idx >> 22;
  size_t base = (size_t)(b * T_ + t) * QKVW + which * 2048 + h * 128 + i;
  float t1 = b2f(qkv[base]), t2 = b2f(qkv[base + 64]);
  // div_i = 10000^(-i/64) ; log2(10000)/64 = 0.20762050593046439
  float ang = (float)t * exp2f(-(float)i * 0.20762050593046439f);
  float sn, cs;
  sincosf(ang, &sn, &cs);
  qkv[base]      = f2b(t1 * cs - t2 * sn);
  qkv[base + 64] = f2b(t2 * cs + t1 * sn);
}

// ---------------- transpose V -> Vt [B*H][D][T] (bf16) ----------------
__global__ __launch_bounds__(256) void vtrans(const u16* __restrict__ qkv, u16* __restrict__ vt) {
  __shared__ __align__(16) u16 ld[128][136];
  const int tt = blockIdx.x, bh = blockIdx.y;
  const int b = bh >> 4, h = bh & 15;
  const u16* vb = qkv + (size_t)b * T_ * QKVW + 4096 + h * 128;
  const int tid = threadIdx.x;
#pragma unroll
  for (int s = 0; s < 8; ++s) {
    int t = (tid >> 4) + s * 16;
    int d0 = (tid & 15) * 8;
    *(bf16x8*)&ld[t][d0] = *(const bf16x8*)(vb + (size_t)(tt * 128 + t) * QKVW + d0);
  }
  __syncthreads();
  u16* vout = vt + (size_t)bh * D_ * T_ + tt * 128;
#pragma unroll
  for (int s = 0; s < 8; ++s) {
    int d = (tid >> 4) + s * 16;
    int t0 = (tid & 15) * 8;
    u16x8 o;
#pragma unroll
    for (int j = 0; j < 8; ++j) o[j] = ld[t0 + j][d];
    *(u16x8*)(vout + (size_t)d * T_ + t0) = o;
  }
}

// ---------------- flash attention (causal, online softmax) ----------------
// grid(512); decode id -> (bh, qt) with complementary qt pairing so each CU's
// two resident blocks sum to 17 tile-iters (was: both blocks same qt -> 2x
// makespan). 256 threads = 4 waves, wave handles 32 q-rows.
// LDS: lKP = K tile (reused as P), lV = Vt tile. 64 KiB -> 2 blocks/CU.
// All tiles use XOR chunk swizzle: 16B-chunk physical = logical ^ (row&7),
// making each 8-lane phase of ds_read_b128 bank-conflict-free.
// NOTE reference gotcha: out = einsum('bhts,bshd->bhtd').reshape(B,T,C) is a
// FLAT reshape of (B,H,T,D): element (b,h,t,d) sits at ((b*H+h)*T+t)*D+d.
__global__ __launch_bounds__(256, 2) void attn(const u16* __restrict__ qkv,
                                               const u16* __restrict__ vt,
                                               u16* __restrict__ obuf) {
  __shared__ __align__(16) u16 lKP[16384];
  __shared__ __align__(16) u16 lV[16384];
  const int tid = threadIdx.x, lane = tid & 63, w = tid >> 6;
  const int quad = lane >> 4, l15 = lane & 15;
  const int id = blockIdx.x;
  const int bh = id & 31;
  const int q5 = id >> 5;
  const int qt = (q5 < 8) ? q5 : 23 - q5;   // CU pairing: qt and 15-qt
  const int b = bh >> 4, h = bh & 15;
  const u16* qb = qkv + (size_t)b * T_ * QKVW + h * 128;
  const u16* kb = qb + 2048;
  const u16* vtb = vt + (size_t)bh * D_ * T_;

  const int q0 = qt * 128 + w * 32;
  bf16x8 qf[2][4];
#pragma unroll
  for (int mi = 0; mi < 2; ++mi)
#pragma unroll
    for (int kk = 0; kk < 4; ++kk)
      qf[mi][kk] = *(const bf16x8*)(qb + (size_t)(q0 + mi * 16 + l15) * QKVW + kk * 32 + quad * 8);

  f32x4 oacc[2][8] = {};
  float mrow[2][4], lrow[2][4];
#pragma unroll
  for (int mi = 0; mi < 2; ++mi)
#pragma unroll
    for (int r = 0; r < 4; ++r) { mrow[mi][r] = -__builtin_inff(); lrow[mi][r] = 0.f; }
  const float sc = 0.08838834764831845f * 1.4426950408889634f;  // 1/sqrt(128) * log2(e)

  for (int kt = 0; kt <= qt; ++kt) {
    // stage K tile [key][d] and Vt tile [d][key], XOR-swizzled chunks
#pragma unroll
    for (int s = 0; s < 8; ++s) {
      int ch = tid + s * 256;            // 0..2047
      int row = ch >> 4, cp = ch & 15;
      int c8 = (cp ^ (row & 7)) * 8;     // swizzled global chunk offset (u16)
      gl_lds16(kb + (size_t)(kt * 128 + row) * QKVW + c8, &lKP[ch * 8]);
      gl_lds16(vtb + (size_t)row * T_ + kt * 128 + c8, &lV[ch * 8]);
    }
    __syncthreads();

    // S = Q K^T
    f32x4 sacc[2][8] = {};
#pragma unroll
    for (int kk = 0; kk < 4; ++kk) {
      bf16x8 kf[8];
#pragma unroll
      for (int nj = 0; nj < 8; ++nj)
        kf[nj] = *(const bf16x8*)&lKP[(nj * 16 + l15) * 128 + ((kk * 4 + quad) ^ (l15 & 7)) * 8];
#pragma unroll
      for (int mi = 0; mi < 2; ++mi)
#pragma unroll
        for (int nj = 0; nj < 8; ++nj)
          sacc[mi][nj] = __builtin_amdgcn_mfma_f32_16x16x32_bf16(qf[mi][kk], kf[nj], sacc[mi][nj], 0, 0, 0);
    }
    __syncthreads();   // all waves done reading K before P overwrites lKP

    const bool diag = (kt == qt);
#pragma unroll
    for (int mi = 0; mi < 2; ++mi) {
      // scale + causal mask in place
#pragma unroll
      for (int nj = 0; nj < 8; ++nj) {
        int key = nj * 16 + l15;
#pragma unroll
        for (int r = 0; r < 4; ++r) {
          float s = sacc[mi][nj][r] * sc;
          if (diag) {
            int qrow = w * 32 + mi * 16 + quad * 4 + r;
            if (key > qrow) s = -__builtin_inff();
          }
          sacc[mi][nj][r] = s;
        }
      }
#pragma unroll
      for (int r = 0; r < 4; ++r) {
        float rm = sacc[mi][0][r];
#pragma unroll
        for (int nj = 1; nj < 8; ++nj) rm = fmaxf(rm, sacc[mi][nj][r]);
        rm = fmaxf(rm, __shfl_xor(rm, 1));
        rm = fmaxf(rm, __shfl_xor(rm, 2));
        rm = fmaxf(rm, __shfl_xor(rm, 4));
        rm = fmaxf(rm, __shfl_xor(rm, 8));
        float mold = mrow[mi][r];
        float mnew = fmaxf(mold, rm);
        float alpha = exp2f(mold - mnew);
        float rs = 0.f;
        int prow = w * 32 + mi * 16 + quad * 4 + r;
        int e = prow & 7;
#pragma unroll
        for (int nj = 0; nj < 8; ++nj) {
          float p = exp2f(sacc[mi][nj][r] - mnew);
          rs += p;
          lKP[prow * 128 + ((2 * nj + (l15 >> 3)) ^ e) * 8 + (l15 & 7)] = f2b(p);
        }
        rs += __shfl_xor(rs, 1);
        rs += __shfl_xor(rs, 2);
        rs += __shfl_xor(rs, 4);
        rs += __shfl_xor(rs, 8);
        mrow[mi][r] = mnew;
        lrow[mi][r] = lrow[mi][r] * alpha + rs;
#pragma unroll
        for (int nd = 0; nd < 8; ++nd) oacc[mi][nd][r] *= alpha;
      }
    }
    // PV: O += P * V   (P from own wave's LDS rows; Vt gives contiguous-k B-frags)
#pragma unroll
    for (int kk = 0; kk < 4; ++kk) {
      bf16x8 pf[2], vf[8];
#pragma unroll
      for (int mi = 0; mi < 2; ++mi)
        pf[mi] = *(const bf16x8*)&lKP[(w * 32 + mi * 16 + l15) * 128 + ((kk * 4 + quad) ^ (l15 & 7)) * 8];
#pragma unroll
      for (int nd = 0; nd < 8; ++nd)
        vf[nd] = *(const bf16x8*)&lV[(nd * 16 + l15) * 128 + ((kk * 4 + quad) ^ (l15 & 7)) * 8];
#pragma unroll
      for (int mi = 0; mi < 2; ++mi)
#pragma unroll
        for (int nd = 0; nd < 8; ++nd)
          oacc[mi][nd] = __builtin_amdgcn_mfma_f32_16x16x32_bf16(pf[mi], vf[nd], oacc[mi][nd], 0, 0, 0);
    }
    __syncthreads();   // before next iteration restages lKP / lV
  }

  // epilogue: O / l -> bf16, REFERENCE-MATCHED layout [B*H][T][D] (see note above)
#pragma unroll
  for (int mi = 0; mi < 2; ++mi)
#pragma unroll
    for (int nd = 0; nd < 8; ++nd)
#pragma unroll
      for (int r = 0; r < 4; ++r) {
        int qrow = q0 + mi * 16 + quad * 4 + r;       // global t
        int dcol = nd * 16 + l15;                     // d 0..127
        float v = oacc[mi][nd][r] / lrow[mi][r];
        obuf[((size_t)bh * T_ + qrow) * D_ + dcol] = f2b(v);
      }
}

extern "C" void kernel_launch(void* const* d_in, const int* in_sizes, int n_in,
                              void* d_out, int out_size, void* d_ws, size_t ws_size,
                              hipStream_t stream) {
  const float* x = (const float*)d_in[0];
  const float* Wqkv = (const float*)d_in[1];
  const float* Wout = (const float*)d_in[2];
  float* out = (float*)d_out;
  char* ws = (char*)d_ws;

  // workspace layout (bytes):
  //   [0,            16777216)  xb (x bf16)   -- later reused as Ob (attn out bf16)
  //   [16777216,     41943040)  Wqkv_t bf16   -- later reused as Wout_t bf16
  //   [41943040,     92274688)  qkv bf16 [4096][6144]
  //   [92274688,    109051904)  Vt bf16 [B*H][128][2048]
  u16* xb   = (u16*)ws;
  u16* wqt  = (u16*)(ws + 16777216);
  u16* qkvb = (u16*)(ws + 41943040);
  u16* vtb  = (u16*)(ws + 92274688);
  u16* wot  = wqt;   // alias: cast after GEMM1 consumed Wqkv_t
  u16* ob   = xb;    // alias: attn output after GEMM1 consumed xb

  castbf<<<4096, 256, 0, stream>>>(x, xb);                                  // 8.4M elems
  castT<<<dim3(96, 32), 256, 0, stream>>>(Wqkv, wqt, 2048, 6144);
  gemm_bt<1><<<dim3(48, 32), 256, 0, stream>>>(xb, wqt, qkvb, 4096, 6144, 2048);
  castT<<<dim3(32, 32), 256, 0, stream>>>(Wout, wot, 2048, 2048);
  rope_k<<<32768, 256, 0, stream>>>(qkvb);
  vtrans<<<dim3(16, 32), 256, 0, stream>>>(qkvb, vtb);
  attn<<<512, 256, 0, stream>>>(qkvb, vtb, ob);
  gemm_bt<0><<<dim3(16, 32), 256, 0, stream>>>(ob, wot, out, 4096, 2048, 2048);
}

// Round 5
// 614.811 us; speedup vs baseline: 1.1664x; 1.1664x over previous
//
#include <hip/hip_runtime.h>

typedef unsigned short u16;
typedef __attribute__((ext_vector_type(8))) short bf16x8;
typedef __attribute__((ext_vector_type(4))) float f32x4;
typedef __attribute__((ext_vector_type(8))) unsigned short u16x8;

#define B_ 2
#define T_ 2048
#define C_ 2048
#define H_ 16
#define D_ 128
#define QKVW 6144  // 3*C

__device__ __forceinline__ u16 f2b(float f) {
  unsigned int x = __builtin_bit_cast(unsigned int, f);
  x += 0x7fffu + ((x >> 16) & 1u);   // round-to-nearest-even
  return (u16)(x >> 16);
}
__device__ __forceinline__ float b2f(u16 u) {
  unsigned int x = ((unsigned int)u) << 16;
  return __builtin_bit_cast(float, x);
}
__device__ __forceinline__ void gl_lds16(const void* g, void* l) {
  __builtin_amdgcn_global_load_lds((const __attribute__((address_space(1))) void*)g,
                                   (__attribute__((address_space(3))) void*)l, 16, 0, 0);
}

// ---------------- cast fp32 -> bf16 (8 elems/thread) ----------------
__global__ void castbf(const float* __restrict__ in, u16* __restrict__ out) {
  int i = blockIdx.x * 256 + threadIdx.x;
  f32x4 a = ((const f32x4*)in)[2 * i];
  f32x4 b = ((const f32x4*)in)[2 * i + 1];
  u16x8 o;
  o[0] = f2b(a[0]); o[1] = f2b(a[1]); o[2] = f2b(a[2]); o[3] = f2b(a[3]);
  o[4] = f2b(b[0]); o[5] = f2b(b[1]); o[6] = f2b(b[2]); o[7] = f2b(b[3]);
  ((u16x8*)out)[i] = o;
}

// ------------- cast + transpose: in [K][N] fp32 -> out [N][K] bf16 -------------
__global__ __launch_bounds__(256) void castT(const float* __restrict__ in,
                                             u16* __restrict__ out, int K, int N) {
  __shared__ __align__(16) u16 ld[64][72];
  const int nt = blockIdx.x * 64, kt = blockIdx.y * 64;
  const int tid = threadIdx.x;
#pragma unroll
  for (int s = 0; s < 4; ++s) {
    int idx = tid + s * 256;        // 0..1023
    int r = idx >> 4;               // k row 0..63
    int c = (idx & 15) * 4;         // n col
    f32x4 v = *(const f32x4*)(in + (size_t)(kt + r) * N + nt + c);
    ld[r][c] = f2b(v[0]); ld[r][c + 1] = f2b(v[1]);
    ld[r][c + 2] = f2b(v[2]); ld[r][c + 3] = f2b(v[3]);
  }
  __syncthreads();
#pragma unroll
  for (int s = 0; s < 2; ++s) {
    int idx = tid + s * 256;        // 0..511
    int n = idx >> 3;               // 0..63
    int c8 = (idx & 7) * 8;         // k offset
    u16x8 o;
#pragma unroll
    for (int j = 0; j < 8; ++j) o[j] = ld[c8 + j][n];
    *(u16x8*)(out + (size_t)(nt + n) * K + kt + c8) = o;
  }
}

// ---------------- GEMM: C[m][n] = sum_k A[m][k] * Bt[n][k], bf16 MFMA ----------------
// 128x128 tile, BK=32, 256 threads = 4 waves (2x2 of 64x64), m97-style staging.
// (round-3 form; round-4's chunk swizzle regressed global coalescing — reverted)
template <int OUT_BF16>
__global__ __launch_bounds__(256) void gemm_bt(const u16* __restrict__ A,
                                               const u16* __restrict__ Bt,
                                               void* __restrict__ Cout,
                                               int M, int N, int K) {
  __shared__ __align__(16) u16 lA[128 * 32];
  __shared__ __align__(16) u16 lB[128 * 32];
  const int tid = threadIdx.x;
  const int lane = tid & 63, w = tid >> 6;
  const int quad = lane >> 4, l15 = lane & 15;
  const int tn0 = blockIdx.x * 128, tm0 = blockIdx.y * 128;
  const int wr = (w >> 1) * 64, wc = (w & 1) * 64;
  f32x4 acc[4][4] = {};

  for (int k0 = 0; k0 < K; k0 += 32) {
#pragma unroll
    for (int s = 0; s < 2; ++s) {
      int ch = tid + s * 256;               // 0..511
      int row = ch >> 2, kc = (ch & 3) * 8;
      gl_lds16(A + (size_t)(tm0 + row) * K + k0 + kc, &lA[ch * 8]);
      gl_lds16(Bt + (size_t)(tn0 + row) * K + k0 + kc, &lB[ch * 8]);
    }
    __syncthreads();
    bf16x8 af[4], bfv[4];
#pragma unroll
    for (int mi = 0; mi < 4; ++mi)
      af[mi] = *(const bf16x8*)&lA[(wr + mi * 16 + l15) * 32 + quad * 8];
#pragma unroll
    for (int ni = 0; ni < 4; ++ni)
      bfv[ni] = *(const bf16x8*)&lB[(wc + ni * 16 + l15) * 32 + quad * 8];
#pragma unroll
    for (int mi = 0; mi < 4; ++mi)
#pragma unroll
      for (int ni = 0; ni < 4; ++ni)
        acc[mi][ni] = __builtin_amdgcn_mfma_f32_16x16x32_bf16(af[mi], bfv[ni], acc[mi][ni], 0, 0, 0);
    __syncthreads();
  }
  // epilogue: C/D layout col=lane&15, row=quad*4+reg
#pragma unroll
  for (int mi = 0; mi < 4; ++mi)
#pragma unroll
    for (int ni = 0; ni < 4; ++ni)
#pragma unroll
      for (int r = 0; r < 4; ++r) {
        int row = tm0 + wr + mi * 16 + quad * 4 + r;
        int col = tn0 + wc + ni * 16 + l15;
        float v = acc[mi][ni][r];
        if (OUT_BF16) ((u16*)Cout)[(size_t)row * N + col] = f2b(v);
        else          ((float*)Cout)[(size_t)row * N + col] = v;
      }
}

// ---------------- RoPE in-place on q,k of qkv (bf16) ----------------
__global__ void rope_k(u16* __restrict__ qkv) {
  int idx = blockIdx.x * 256 + threadIdx.x;   // 0 .. 2^23-1
  int i = idx & 63;
  int h = (idx >> 6) & 15;
  int which = (idx >> 10) & 1;
  int t = (idx >> 11) & 2047;
  int b = idx >> 22;
  size_t base = (size_t)(b * T_ + t) * QKVW + which * 2048 + h * 128 + i;
  float t1 = b2f(qkv[base]), t2 = b2f(qkv[base + 64]);
  // div_i = 10000^(-i/64) ; log2(10000)/64 = 0.20762050593046439
  float ang = (float)t * exp2f(-(float)i * 0.20762050593046439f);
  float sn, cs;
  sincosf(ang, &sn, &cs);
  qkv[base]      = f2b(t1 * cs - t2 * sn);
  qkv[base + 64] = f2b(t2 * cs + t1 * sn);
}

// ---------------- transpose V -> Vt [B*H][D][T] (bf16) ----------------
__global__ __launch_bounds__(256) void vtrans(const u16* __restrict__ qkv, u16* __restrict__ vt) {
  __shared__ __align__(16) u16 ld[128][136];
  const int tt = blockIdx.x, bh = blockIdx.y;
  const int b = bh >> 4, h = bh & 15;
  const u16* vb = qkv + (size_t)b * T_ * QKVW + 4096 + h * 128;
  const int tid = threadIdx.x;
#pragma unroll
  for (int s = 0; s < 8; ++s) {
    int t = (tid >> 4) + s * 16;
    int d0 = (tid & 15) * 8;
    *(bf16x8*)&ld[t][d0] = *(const bf16x8*)(vb + (size_t)(tt * 128 + t) * QKVW + d0);
  }
  __syncthreads();
  u16* vout = vt + (size_t)bh * D_ * T_ + tt * 128;
#pragma unroll
  for (int s = 0; s < 8; ++s) {
    int d = (tid >> 4) + s * 16;
    int t0 = (tid & 15) * 8;
    u16x8 o;
#pragma unroll
    for (int j = 0; j < 8; ++j) o[j] = ld[t0 + j][d];
    *(u16x8*)(vout + (size_t)d * T_ + t0) = o;
  }
}

// ---------------- flash attention (causal, online softmax) ----------------
// R5: 64-q-row x 64-key tiles, 32 KB LDS/block -> 4 blocks/CU (latency-bound
// kernel needs concurrency, R4 post-mortem). grid (32 qtile, 32 bh); 4 waves,
// wave owns 16 q-rows. lK = K tile [64 key][128 d] (reused as P [64 q][64 k]),
// lV = Vt tile [128 d][64 key]. P-store / PV reads are 64B-stride (conflict-
// free); only QK K-frag reads keep 8-way.
// NOTE reference gotcha: out = einsum('bhts,bshd->bhtd').reshape(B,T,C) is a
// FLAT reshape of (B,H,T,D): element (b,h,t,d) sits at ((b*H+h)*T+t)*D+d.
__global__ __launch_bounds__(256, 4) void attn(const u16* __restrict__ qkv,
                                               const u16* __restrict__ vt,
                                               u16* __restrict__ obuf) {
  __shared__ __align__(16) u16 lK[8192];   // 16 KB: K tile / P tile
  __shared__ __align__(16) u16 lV[8192];   // 16 KB: Vt tile
  const int tid = threadIdx.x, lane = tid & 63, w = tid >> 6;
  const int quad = lane >> 4, l15 = lane & 15;
  const int j = blockIdx.x, bh = blockIdx.y;
  const int b = bh >> 4, h = bh & 15;
  const u16* qb = qkv + (size_t)b * T_ * QKVW + h * 128;
  const u16* kb = qb + 2048;
  const u16* vtb = vt + (size_t)bh * D_ * T_;

  const int q0 = j * 64 + w * 16;   // wave's 16 q-rows
  bf16x8 qf[4];
#pragma unroll
  for (int kk = 0; kk < 4; ++kk)
    qf[kk] = *(const bf16x8*)(qb + (size_t)(q0 + l15) * QKVW + kk * 32 + quad * 8);

  f32x4 oacc[8] = {};
  float mrow[4], lrow[4];
#pragma unroll
  for (int r = 0; r < 4; ++r) { mrow[r] = -__builtin_inff(); lrow[r] = 0.f; }
  const float sc = 0.08838834764831845f * 1.4426950408889634f;  // 1/sqrt(128) * log2(e)

  for (int kt = 0; kt <= j; ++kt) {
    // stage K tile [64 key][128 d] and Vt tile [128 d][64 key]
#pragma unroll
    for (int s = 0; s < 4; ++s) {
      int ch = tid + s * 256;                  // 0..1023
      int krow = ch >> 4, kcp = (ch & 15) * 8; // K: 64 rows x 16 chunks
      int vrow = ch >> 3, vcp = (ch & 7) * 8;  // V: 128 rows x 8 chunks
      gl_lds16(kb + (size_t)(kt * 64 + krow) * QKVW + kcp, &lK[ch * 8]);
      gl_lds16(vtb + (size_t)vrow * T_ + kt * 64 + vcp, &lV[ch * 8]);
    }
    __syncthreads();

    // S = Q K^T   (16 q-rows x 64 keys per wave)
    f32x4 sacc[4] = {};
#pragma unroll
    for (int kk = 0; kk < 4; ++kk) {
      bf16x8 kf[4];
#pragma unroll
      for (int nj = 0; nj < 4; ++nj)
        kf[nj] = *(const bf16x8*)&lK[(nj * 16 + l15) * 128 + kk * 32 + quad * 8];
#pragma unroll
      for (int nj = 0; nj < 4; ++nj)
        sacc[nj] = __builtin_amdgcn_mfma_f32_16x16x32_bf16(qf[kk], kf[nj], sacc[nj], 0, 0, 0);
    }
    __syncthreads();   // all waves done reading K before P overwrites lK

    const bool diag = (kt == j);
    // scale + causal mask
#pragma unroll
    for (int nj = 0; nj < 4; ++nj) {
      int key = nj * 16 + l15;                 // local key 0..63
#pragma unroll
      for (int r = 0; r < 4; ++r) {
        float s = sacc[nj][r] * sc;
        if (diag) {
          int qrow = w * 16 + quad * 4 + r;    // local q 0..63
          if (key > qrow) s = -__builtin_inff();
        }
        sacc[nj][r] = s;
      }
    }
#pragma unroll
    for (int r = 0; r < 4; ++r) {
      float rm = sacc[0][r];
#pragma unroll
      for (int nj = 1; nj < 4; ++nj) rm = fmaxf(rm, sacc[nj][r]);
      rm = fmaxf(rm, __shfl_xor(rm, 1));
      rm = fmaxf(rm, __shfl_xor(rm, 2));
      rm = fmaxf(rm, __shfl_xor(rm, 4));
      rm = fmaxf(rm, __shfl_xor(rm, 8));
      float mold = mrow[r];
      float mnew = fmaxf(mold, rm);
      float alpha = exp2f(mold - mnew);
      float rs = 0.f;
      int prow = w * 16 + quad * 4 + r;        // local q row (wave-private)
#pragma unroll
      for (int nj = 0; nj < 4; ++nj) {
        float p = exp2f(sacc[nj][r] - mnew);
        rs += p;
        lK[prow * 64 + nj * 16 + l15] = f2b(p);  // P overlay, 64B row stride
      }
      rs += __shfl_xor(rs, 1);
      rs += __shfl_xor(rs, 2);
      rs += __shfl_xor(rs, 4);
      rs += __shfl_xor(rs, 8);
      mrow[r] = mnew;
      lrow[r] = lrow[r] * alpha + rs;
#pragma unroll
      for (int nd = 0; nd < 8; ++nd) oacc[nd][r] *= alpha;
    }
    // PV: O += P * V  (P rows are wave-private — no barrier needed before this)
#pragma unroll
    for (int kk = 0; kk < 2; ++kk) {
      bf16x8 pf, vf[8];
      pf = *(const bf16x8*)&lK[(w * 16 + l15) * 64 + kk * 32 + quad * 8];
#pragma unroll
      for (int nd = 0; nd < 8; ++nd)
        vf[nd] = *(const bf16x8*)&lV[(nd * 16 + l15) * 64 + kk * 32 + quad * 8];
#pragma unroll
      for (int nd = 0; nd < 8; ++nd)
        oacc[nd] = __builtin_amdgcn_mfma_f32_16x16x32_bf16(pf, vf[nd], oacc[nd], 0, 0, 0);
    }
    __syncthreads();   // before next iteration restages lK / lV
  }

  // epilogue: O / l -> bf16, REFERENCE-MATCHED layout [B*H][T][D] (see note)
#pragma unroll
  for (int nd = 0; nd < 8; ++nd)
#pragma unroll
    for (int r = 0; r < 4; ++r) {
      int qrow = j * 64 + w * 16 + quad * 4 + r;   // global t
      int dcol = nd * 16 + l15;                    // d 0..127
      float v = oacc[nd][r] / lrow[r];
      obuf[((size_t)bh * T_ + qrow) * D_ + dcol] = f2b(v);
    }
}

extern "C" void kernel_launch(void* const* d_in, const int* in_sizes, int n_in,
                              void* d_out, int out_size, void* d_ws, size_t ws_size,
                              hipStream_t stream) {
  const float* x = (const float*)d_in[0];
  const float* Wqkv = (const float*)d_in[1];
  const float* Wout = (const float*)d_in[2];
  float* out = (float*)d_out;
  char* ws = (char*)d_ws;

  // workspace layout (bytes):
  //   [0,            16777216)  xb (x bf16)   -- later reused as Ob (attn out bf16)
  //   [16777216,     41943040)  Wqkv_t bf16   -- later reused as Wout_t bf16
  //   [41943040,     92274688)  qkv bf16 [4096][6144]
  //   [92274688,    109051904)  Vt bf16 [B*H][128][2048]
  u16* xb   = (u16*)ws;
  u16* wqt  = (u16*)(ws + 16777216);
  u16* qkvb = (u16*)(ws + 41943040);
  u16* vtb  = (u16*)(ws + 92274688);
  u16* wot  = wqt;   // alias: cast after GEMM1 consumed Wqkv_t
  u16* ob   = xb;    // alias: attn output after GEMM1 consumed xb

  castbf<<<4096, 256, 0, stream>>>(x, xb);                                  // 8.4M elems
  castT<<<dim3(96, 32), 256, 0, stream>>>(Wqkv, wqt, 2048, 6144);
  gemm_bt<1><<<dim3(48, 32), 256, 0, stream>>>(xb, wqt, qkvb, 4096, 6144, 2048);
  castT<<<dim3(32, 32), 256, 0, stream>>>(Wout, wot, 2048, 2048);
  rope_k<<<32768, 256, 0, stream>>>(qkvb);
  vtrans<<<dim3(16, 32), 256, 0, stream>>>(qkvb, vtb);
  attn<<<dim3(32, 32), 256, 0, stream>>>(qkvb, vtb, ob);
  gemm_bt<0><<<dim3(16, 32), 256, 0, stream>>>(ob, wot, out, 4096, 2048, 2048);
}

// Round 6
// 467.189 us; speedup vs baseline: 1.5349x; 1.3160x over previous
//
#include <hip/hip_runtime.h>

typedef unsigned short u16;
typedef __attribute__((ext_vector_type(8))) short bf16x8;
typedef __attribute__((ext_vector_type(4))) float f32x4;
typedef __attribute__((ext_vector_type(8))) unsigned short u16x8;

#define B_ 2
#define T_ 2048
#define C_ 2048
#define H_ 16
#define D_ 128
#define QKVW 6144  // 3*C

__device__ __forceinline__ u16 f2b(float f) {
  unsigned int x = __builtin_bit_cast(unsigned int, f);
  x += 0x7fffu + ((x >> 16) & 1u);   // round-to-nearest-even
  return (u16)(x >> 16);
}
__device__ __forceinline__ float b2f(u16 u) {
  unsigned int x = ((unsigned int)u) << 16;
  return __builtin_bit_cast(float, x);
}
__device__ __forceinline__ void gl_lds16(const void* g, void* l) {
  __builtin_amdgcn_global_load_lds((const __attribute__((address_space(1))) void*)g,
                                   (__attribute__((address_space(3))) void*)l, 16, 0, 0);
}

// ---------------- cast fp32 -> bf16 (8 elems/thread) ----------------
__global__ void castbf(const float* __restrict__ in, u16* __restrict__ out) {
  int i = blockIdx.x * 256 + threadIdx.x;
  f32x4 a = ((const f32x4*)in)[2 * i];
  f32x4 b = ((const f32x4*)in)[2 * i + 1];
  u16x8 o;
  o[0] = f2b(a[0]); o[1] = f2b(a[1]); o[2] = f2b(a[2]); o[3] = f2b(a[3]);
  o[4] = f2b(b[0]); o[5] = f2b(b[1]); o[6] = f2b(b[2]); o[7] = f2b(b[3]);
  ((u16x8*)out)[i] = o;
}

// ------------- cast + transpose: in [K][N] fp32 -> out [N][K] bf16 -------------
__global__ __launch_bounds__(256) void castT(const float* __restrict__ in,
                                             u16* __restrict__ out, int K, int N) {
  __shared__ __align__(16) u16 ld[64][72];
  const int nt = blockIdx.x * 64, kt = blockIdx.y * 64;
  const int tid = threadIdx.x;
#pragma unroll
  for (int s = 0; s < 4; ++s) {
    int idx = tid + s * 256;        // 0..1023
    int r = idx >> 4;               // k row 0..63
    int c = (idx & 15) * 4;         // n col
    f32x4 v = *(const f32x4*)(in + (size_t)(kt + r) * N + nt + c);
    ld[r][c] = f2b(v[0]); ld[r][c + 1] = f2b(v[1]);
    ld[r][c + 2] = f2b(v[2]); ld[r][c + 3] = f2b(v[3]);
  }
  __syncthreads();
#pragma unroll
  for (int s = 0; s < 2; ++s) {
    int idx = tid + s * 256;        // 0..511
    int n = idx >> 3;               // 0..63
    int c8 = (idx & 7) * 8;         // k offset
    u16x8 o;
#pragma unroll
    for (int j = 0; j < 8; ++j) o[j] = ld[c8 + j][n];
    *(u16x8*)(out + (size_t)(nt + n) * K + kt + c8) = o;
  }
}

// ---------------- GEMM: C[m][n] = sum_k A[m][k] * Bt[n][k], bf16 MFMA ----------------
// 128x128 tile, BK=32, 256 threads = 4 waves (2x2 of 64x64), m97-style staging.
template <int OUT_BF16>
__global__ __launch_bounds__(256) void gemm_bt(const u16* __restrict__ A,
                                               const u16* __restrict__ Bt,
                                               void* __restrict__ Cout,
                                               int M, int N, int K) {
  __shared__ __align__(16) u16 lA[128 * 32];
  __shared__ __align__(16) u16 lB[128 * 32];
  const int tid = threadIdx.x;
  const int lane = tid & 63, w = tid >> 6;
  const int quad = lane >> 4, l15 = lane & 15;
  const int tn0 = blockIdx.x * 128, tm0 = blockIdx.y * 128;
  const int wr = (w >> 1) * 64, wc = (w & 1) * 64;
  f32x4 acc[4][4] = {};

  for (int k0 = 0; k0 < K; k0 += 32) {
#pragma unroll
    for (int s = 0; s < 2; ++s) {
      int ch = tid + s * 256;               // 0..511
      int row = ch >> 2, kc = (ch & 3) * 8;
      gl_lds16(A + (size_t)(tm0 + row) * K + k0 + kc, &lA[ch * 8]);
      gl_lds16(Bt + (size_t)(tn0 + row) * K + k0 + kc, &lB[ch * 8]);
    }
    __syncthreads();
    bf16x8 af[4], bfv[4];
#pragma unroll
    for (int mi = 0; mi < 4; ++mi)
      af[mi] = *(const bf16x8*)&lA[(wr + mi * 16 + l15) * 32 + quad * 8];
#pragma unroll
    for (int ni = 0; ni < 4; ++ni)
      bfv[ni] = *(const bf16x8*)&lB[(wc + ni * 16 + l15) * 32 + quad * 8];
#pragma unroll
    for (int mi = 0; mi < 4; ++mi)
#pragma unroll
      for (int ni = 0; ni < 4; ++ni)
        acc[mi][ni] = __builtin_amdgcn_mfma_f32_16x16x32_bf16(af[mi], bfv[ni], acc[mi][ni], 0, 0, 0);
    __syncthreads();
  }
  // epilogue: C/D layout col=lane&15, row=quad*4+reg
#pragma unroll
  for (int mi = 0; mi < 4; ++mi)
#pragma unroll
    for (int ni = 0; ni < 4; ++ni)
#pragma unroll
      for (int r = 0; r < 4; ++r) {
        int row = tm0 + wr + mi * 16 + quad * 4 + r;
        int col = tn0 + wc + ni * 16 + l15;
        float v = acc[mi][ni][r];
        if (OUT_BF16) ((u16*)Cout)[(size_t)row * N + col] = f2b(v);
        else          ((float*)Cout)[(size_t)row * N + col] = v;
      }
}

// ---------------- RoPE in-place on q,k of qkv (bf16) ----------------
__global__ void rope_k(u16* __restrict__ qkv) {
  int idx = blockIdx.x * 256 + threadIdx.x;   // 0 .. 2^23-1
  int i = idx & 63;
  int h = (idx >> 6) & 15;
  int which = (idx >> 10) & 1;
  int t = (idx >> 11) & 2047;
  int b = idx >> 22;
  size_t base = (size_t)(b * T_ + t) * QKVW + which * 2048 + h * 128 + i;
  float t1 = b2f(qkv[base]), t2 = b2f(qkv[base + 64]);
  // div_i = 10000^(-i/64) ; log2(10000)/64 = 0.20762050593046439
  float ang = (float)t * exp2f(-(float)i * 0.20762050593046439f);
  float sn, cs;
  sincosf(ang, &sn, &cs);
  qkv[base]      = f2b(t1 * cs - t2 * sn);
  qkv[base + 64] = f2b(t2 * cs + t1 * sn);
}

// ---------------- transpose V -> Vt [B*H][D][T] (bf16) ----------------
__global__ __launch_bounds__(256) void vtrans(const u16* __restrict__ qkv, u16* __restrict__ vt) {
  __shared__ __align__(16) u16 ld[128][136];
  const int tt = blockIdx.x, bh = blockIdx.y;
  const int b = bh >> 4, h = bh & 15;
  const u16* vb = qkv + (size_t)b * T_ * QKVW + 4096 + h * 128;
  const int tid = threadIdx.x;
#pragma unroll
  for (int s = 0; s < 8; ++s) {
    int t = (tid >> 4) + s * 16;
    int d0 = (tid & 15) * 8;
    *(bf16x8*)&ld[t][d0] = *(const bf16x8*)(vb + (size_t)(tt * 128 + t) * QKVW + d0);
  }
  __syncthreads();
  u16* vout = vt + (size_t)bh * D_ * T_ + tt * 128;
#pragma unroll
  for (int s = 0; s < 8; ++s) {
    int d = (tid >> 4) + s * 16;
    int t0 = (tid & 15) * 8;
    u16x8 o;
#pragma unroll
    for (int j = 0; j < 8; ++j) o[j] = ld[t0 + j][d];
    *(u16x8*)(vout + (size_t)d * T_ + t0) = o;
  }
}

// ---------------- flash attention (causal, online softmax) ----------------
// R6: LDS-pipe de-conflict. R5 post-mortem: every ds_read_b128 phase (16
// lanes) hit one 4-bank group (power-of-2 row stride) = 16-way conflict;
// LDS pipe saturated (~3250 clk/block-iter vs 736 clean). Fix: stage via
// VGPR round-trip (coalesced global loads + ds_write_b128) into PADDED
// tiles: lK [64][136], lV [128][72] (+8 u16 pad -> banks rotate 4/row ->
// fragment reads and staging writes conflict-free). 35 KB LDS, 4 blocks/CU.
// Grid swapped to (bh, j): each CU's 4 resident blocks get j spread
// {j0, j0+8, j0+16, j0+24} (work [52,80] vs same-j [4,128]).
// NOTE reference gotcha: out = einsum('bhts,bshd->bhtd').reshape(B,T,C) is a
// FLAT reshape of (B,H,T,D): element (b,h,t,d) sits at ((b*H+h)*T+t)*D+d.
#define LKW 136   // K/P tile row stride (u16)
#define LVW 72    // V tile row stride (u16)
__global__ __launch_bounds__(256, 4) void attn(const u16* __restrict__ qkv,
                                               const u16* __restrict__ vt,
                                               u16* __restrict__ obuf) {
  __shared__ __align__(16) u16 lK[64 * LKW];    // 17408 B: K tile / P tile
  __shared__ __align__(16) u16 lV[128 * LVW];   // 18432 B: Vt tile
  const int tid = threadIdx.x, lane = tid & 63, w = tid >> 6;
  const int quad = lane >> 4, l15 = lane & 15;
  const int bh = blockIdx.x, j = blockIdx.y;
  const int b = bh >> 4, h = bh & 15;
  const u16* qb = qkv + (size_t)b * T_ * QKVW + h * 128;
  const u16* kb = qb + 2048;
  const u16* vtb = vt + (size_t)bh * D_ * T_;

  const int q0 = j * 64 + w * 16;   // wave's 16 q-rows
  bf16x8 qf[4];
#pragma unroll
  for (int kk = 0; kk < 4; ++kk)
    qf[kk] = *(const bf16x8*)(qb + (size_t)(q0 + l15) * QKVW + kk * 32 + quad * 8);

  f32x4 oacc[8] = {};
  float mrow[4], lrow[4];
#pragma unroll
  for (int r = 0; r < 4; ++r) { mrow[r] = -__builtin_inff(); lrow[r] = 0.f; }
  const float sc = 0.08838834764831845f * 1.4426950408889634f;  // 1/sqrt(128) * log2(e)

  for (int kt = 0; kt <= j; ++kt) {
    // stage K tile [64 key][128 d] and Vt tile [128 d][64 key] via VGPR
    // round-trip into padded LDS (global loads coalesced: 16 lanes = 256B row
    // for K, 8 lanes = 128B row-segment for V).
    u16x8 kst[4], vst[4];
#pragma unroll
    for (int s = 0; s < 4; ++s) {
      int ch = tid + s * 256;                  // 0..1023
      int krow = ch >> 4, kcp = ch & 15;
      kst[s] = *(const u16x8*)(kb + (size_t)(kt * 64 + krow) * QKVW + kcp * 8);
      int vrow = ch >> 3, vcp = ch & 7;
      vst[s] = *(const u16x8*)(vtb + (size_t)vrow * T_ + kt * 64 + vcp * 8);
    }
#pragma unroll
    for (int s = 0; s < 4; ++s) {
      int ch = tid + s * 256;
      int krow = ch >> 4, kcp = ch & 15;
      *(u16x8*)&lK[krow * LKW + kcp * 8] = kst[s];
      int vrow = ch >> 3, vcp = ch & 7;
      *(u16x8*)&lV[vrow * LVW + vcp * 8] = vst[s];
    }
    __syncthreads();

    // S = Q K^T   (16 q-rows x 64 keys per wave)
    f32x4 sacc[4] = {};
#pragma unroll
    for (int kk = 0; kk < 4; ++kk) {
      bf16x8 kf[4];
#pragma unroll
      for (int nj = 0; nj < 4; ++nj)
        kf[nj] = *(const bf16x8*)&lK[(nj * 16 + l15) * LKW + kk * 32 + quad * 8];
#pragma unroll
      for (int nj = 0; nj < 4; ++nj)
        sacc[nj] = __builtin_amdgcn_mfma_f32_16x16x32_bf16(qf[kk], kf[nj], sacc[nj], 0, 0, 0);
    }
    __syncthreads();   // all waves done reading K before P overwrites lK

    const bool diag = (kt == j);
    // scale + causal mask
#pragma unroll
    for (int nj = 0; nj < 4; ++nj) {
      int key = nj * 16 + l15;                 // local key 0..63
#pragma unroll
      for (int r = 0; r < 4; ++r) {
        float s = sacc[nj][r] * sc;
        if (diag) {
          int qrow = w * 16 + quad * 4 + r;    // local q 0..63
          if (key > qrow) s = -__builtin_inff();
        }
        sacc[nj][r] = s;
      }
    }
#pragma unroll
    for (int r = 0; r < 4; ++r) {
      float rm = sacc[0][r];
#pragma unroll
      for (int nj = 1; nj < 4; ++nj) rm = fmaxf(rm, sacc[nj][r]);
      rm = fmaxf(rm, __shfl_xor(rm, 1));
      rm = fmaxf(rm, __shfl_xor(rm, 2));
      rm = fmaxf(rm, __shfl_xor(rm, 4));
      rm = fmaxf(rm, __shfl_xor(rm, 8));
      float mold = mrow[r];
      float mnew = fmaxf(mold, rm);
      float alpha = exp2f(mold - mnew);
      float rs = 0.f;
      int prow = w * 16 + quad * 4 + r;        // local q row (wave-private)
#pragma unroll
      for (int nj = 0; nj < 4; ++nj) {
        float p = exp2f(sacc[nj][r] - mnew);
        rs += p;
        lK[prow * LKW + nj * 16 + l15] = f2b(p);  // P overlay, padded stride
      }
      rs += __shfl_xor(rs, 1);
      rs += __shfl_xor(rs, 2);
      rs += __shfl_xor(rs, 4);
      rs += __shfl_xor(rs, 8);
      mrow[r] = mnew;
      lrow[r] = lrow[r] * alpha + rs;
#pragma unroll
      for (int nd = 0; nd < 8; ++nd) oacc[nd][r] *= alpha;
    }
    // PV: O += P * V  (P rows are wave-private — no barrier needed before this)
#pragma unroll
    for (int kk = 0; kk < 2; ++kk) {
      bf16x8 pf, vf[8];
      pf = *(const bf16x8*)&lK[(w * 16 + l15) * LKW + kk * 32 + quad * 8];
#pragma unroll
      for (int nd = 0; nd < 8; ++nd)
        vf[nd] = *(const bf16x8*)&lV[(nd * 16 + l15) * LVW + kk * 32 + quad * 8];
#pragma unroll
      for (int nd = 0; nd < 8; ++nd)
        oacc[nd] = __builtin_amdgcn_mfma_f32_16x16x32_bf16(pf, vf[nd], oacc[nd], 0, 0, 0);
    }
    __syncthreads();   // before next iteration restages lK / lV
  }

  // epilogue: O / l -> bf16, REFERENCE-MATCHED layout [B*H][T][D] (see note)
#pragma unroll
  for (int nd = 0; nd < 8; ++nd)
#pragma unroll
    for (int r = 0; r < 4; ++r) {
      int qrow = j * 64 + w * 16 + quad * 4 + r;   // global t
      int dcol = nd * 16 + l15;                    // d 0..127
      float v = oacc[nd][r] / lrow[r];
      obuf[((size_t)bh * T_ + qrow) * D_ + dcol] = f2b(v);
    }
}

extern "C" void kernel_launch(void* const* d_in, const int* in_sizes, int n_in,
                              void* d_out, int out_size, void* d_ws, size_t ws_size,
                              hipStream_t stream) {
  const float* x = (const float*)d_in[0];
  const float* Wqkv = (const float*)d_in[1];
  const float* Wout = (const float*)d_in[2];
  float* out = (float*)d_out;
  char* ws = (char*)d_ws;

  // workspace layout (bytes):
  //   [0,            16777216)  xb (x bf16)   -- later reused as Ob (attn out bf16)
  //   [16777216,     41943040)  Wqkv_t bf16   -- later reused as Wout_t bf16
  //   [41943040,     92274688)  qkv bf16 [4096][6144]
  //   [92274688,    109051904)  Vt bf16 [B*H][128][2048]
  u16* xb   = (u16*)ws;
  u16* wqt  = (u16*)(ws + 16777216);
  u16* qkvb = (u16*)(ws + 41943040);
  u16* vtb  = (u16*)(ws + 92274688);
  u16* wot  = wqt;   // alias: cast after GEMM1 consumed Wqkv_t
  u16* ob   = xb;    // alias: attn output after GEMM1 consumed xb

  castbf<<<4096, 256, 0, stream>>>(x, xb);                                  // 8.4M elems
  castT<<<dim3(96, 32), 256, 0, stream>>>(Wqkv, wqt, 2048, 6144);
  gemm_bt<1><<<dim3(48, 32), 256, 0, stream>>>(xb, wqt, qkvb, 4096, 6144, 2048);
  castT<<<dim3(32, 32), 256, 0, stream>>>(Wout, wot, 2048, 2048);
  rope_k<<<32768, 256, 0, stream>>>(qkvb);
  vtrans<<<dim3(16, 32), 256, 0, stream>>>(qkvb, vtb);
  attn<<<dim3(32, 32), 256, 0, stream>>>(qkvb, vtb, ob);   // (bh, j)
  gemm_bt<0><<<dim3(16, 32), 256, 0, stream>>>(ob, wot, out, 4096, 2048, 2048);
}